// Round 1
// baseline (84.752 us; speedup 1.0000x reference)
//
#include <hip/hip_runtime.h>

// out[b,n] = relu( sum_d x[b, idx[n,d]] * w[n,d] )
//   x: (B=256, N=16384) f32, w: (N,32) f32, idx: (N,32) i32, out: (B,N) f32
//
// R10: R9 structure (direct x->LDS h2 gather image, ds_read_b64 quads,
// pk_fma, split-major grid for XCD L2 reuse) + two stall fixes:
//  1. Half-DEG software pipeline: qd is split into two 8-entry register
//     buffers; half1's pw loads are issued before half0's compute, and the
//     NEXT i's half0 loads are issued between the two compute halves. The
//     i=0 half0 prefetch is issued before __syncthreads (hides under the
//     staging drain). Removes the ~300-500cyc L2-latency bubble that headed
//     every i-iteration (all LDS addresses depend on qd).
//  2. Nontemporal out stores: per-XCD L2 working set was x(2MiB)+pw(2MiB)
//     +out write-allocate(2MiB) > 4MiB L2; NT stores keep x/pw resident.
// Numerics identical to R9 (same packing, same a/c accumulation split).

#define NB   16384
#define DEG  32

typedef __fp16 hp2 __attribute__((ext_vector_type(2)));  // cvt_pkrtz result type

__device__ __forceinline__ unsigned pk16(float a, float b) {
    return __builtin_bit_cast(unsigned, (hp2)__builtin_amdgcn_cvt_pkrtz(a, b));
}

__global__ __launch_bounds__(256) void prep_pw_kernel(
    const int* __restrict__ idx, const float* __restrict__ w,
    uint2* __restrict__ pw) {
    __shared__ int   idx_s[64][33];
    __shared__ float w_s[64][33];
    const int t  = threadIdx.x;
    const int nb = (int)blockIdx.x * 64;

    const int4*   src  = (const int4*)(idx + (size_t)nb * DEG);
    const float4* srcw = (const float4*)(w   + (size_t)nb * DEG);
#pragma unroll
    for (int p = 0; p < 2; ++p) {
        const int e4 = t + 256 * p;              // int4 index 0..511, coalesced
        const int n0 = e4 >> 3;
        const int c0 = (e4 & 7) * 4;
        const int4 v = src[e4];
        idx_s[n0][c0 + 0] = v.x; idx_s[n0][c0 + 1] = v.y;
        idx_s[n0][c0 + 2] = v.z; idx_s[n0][c0 + 3] = v.w;
        const float4 f = srcw[e4];
        w_s[n0][c0 + 0] = f.x; w_s[n0][c0 + 1] = f.y;
        w_s[n0][c0 + 2] = f.z; w_s[n0][c0 + 3] = f.w;
    }
    __syncthreads();

    const int np    = t & 63;
    const int dbase = t >> 6;
#pragma unroll
    for (int k = 0; k < 4; ++k) {
        const int d2 = dbase * 4 + k;            // 0..15
        uint2 o;
        o.x = (unsigned)idx_s[np][2 * d2] | ((unsigned)idx_s[np][2 * d2 + 1] << 16);
        o.y = pk16(w_s[np][2 * d2], w_s[np][2 * d2 + 1]);
        pw[(size_t)d2 * NB + nb + np] = o;
    }
}

// Load one half (8 d2-streams) of the pw row for column n into a register
// buffer. Streams are SGPR-base + shared voffset; all 8 issue back-to-back.
#define LOADH(buf, nn, h)                                                  \
    {                                                                      \
        const uint2* p_ = pw + (size_t)((h) * 8) * NB + (nn);              \
        _Pragma("unroll") for (int d2_ = 0; d2_ < 8; ++d2_)                \
            buf[d2_] = p_[(size_t)d2_ * NB];                               \
    }

// Consume one half: 16 ds_read_b64 gathers + 32 v_pk_fma_f16.
#define ACCH(buf, r01, r23)                                                \
    {                                                                      \
        _Pragma("unroll") for (int d2_ = 0; d2_ < 8; ++d2_) {              \
            const unsigned jp_ = buf[d2_].x;                               \
            const uint2 g0_ = lds[jp_ & 0xffffu];                          \
            const uint2 g1_ = lds[jp_ >> 16];                              \
            const hp2 w2_  = __builtin_bit_cast(hp2, buf[d2_].y);          \
            const hp2 wlo_ = {w2_.x, w2_.x};                               \
            const hp2 whi_ = {w2_.y, w2_.y};                               \
            r01 += wlo_ * __builtin_bit_cast(hp2, g0_.x);                  \
            r23 += wlo_ * __builtin_bit_cast(hp2, g0_.y);                  \
            r01 += whi_ * __builtin_bit_cast(hp2, g1_.x);                  \
            r23 += whi_ * __builtin_bit_cast(hp2, g1_.y);                  \
        }                                                                  \
    }

__global__ __launch_bounds__(1024, 4) void gather4_kernel(
    const float* __restrict__ x, const uint2* __restrict__ pw,
    float* __restrict__ out) {
    extern __shared__ uint2 lds[];               // 16384 uint2 = 128 KiB
    const int t  = threadIdx.x;
    const int q  = (int)blockIdx.x & 63;         // quad 0..63 -> b = 4q..4q+3
    const int n0 = ((int)blockIdx.x >> 6) * 4096;  // split-major: XCD = q%8

    // Stage quad j-image straight from x (coalesced float4 per row; rows are
    // L2-hot for 3 of the 4 split-blocks). ds_write_b128 stride-32B: clean.
    const float* xr0 = x + (size_t)(4 * q) * NB;
    const float* xr1 = xr0 + NB;
    const float* xr2 = xr1 + NB;
    const float* xr3 = xr2 + NB;
#pragma unroll
    for (int p = 0; p < 4; ++p) {
        const int j = 4 * (t + 1024 * p);
        const float4 r0 = *(const float4*)&xr0[j];
        const float4 r1 = *(const float4*)&xr1[j];
        const float4 r2 = *(const float4*)&xr2[j];
        const float4 r3 = *(const float4*)&xr3[j];
        uint4 w0, w1;
        w0.x = pk16(r0.x, r1.x); w0.y = pk16(r2.x, r3.x);
        w0.z = pk16(r0.y, r1.y); w0.w = pk16(r2.y, r3.y);
        w1.x = pk16(r0.z, r1.z); w1.y = pk16(r2.z, r3.z);
        w1.z = pk16(r0.w, r1.w); w1.w = pk16(r2.w, r3.w);
        *(uint4*)&lds[j]     = w0;
        *(uint4*)&lds[j + 2] = w1;
    }

    uint2 qa[8], qb[8];
    // Prefetch i=0 half0 before the barrier: its L2 latency hides under the
    // staging lgkmcnt drain + barrier.
    LOADH(qa, n0 + t, 0);
    __syncthreads();

    const int b0 = 4 * q;
#pragma unroll
    for (int i = 0; i < 4; ++i) {
        const int n = n0 + t + 1024 * i;         // consecutive lanes -> consec n

        LOADH(qb, n, 1);                         // half1 in flight over half0 compute
        hp2 a01 = {0, 0}, a23 = {0, 0}, c01 = {0, 0}, c23 = {0, 0};
        ACCH(qa, a01, a23);                      // waits qa only (vmcnt(8))
        if (i < 3) LOADH(qa, n + 1024, 0);       // next-i half0 over half1 compute
        ACCH(qb, c01, c23);                      // waits qb only

        const hp2 s01 = a01 + c01;
        const hp2 s23 = a23 + c23;
        __builtin_nontemporal_store(fmaxf((float)s01.x, 0.f), &out[(size_t)(b0 + 0) * NB + n]);
        __builtin_nontemporal_store(fmaxf((float)s01.y, 0.f), &out[(size_t)(b0 + 1) * NB + n]);
        __builtin_nontemporal_store(fmaxf((float)s23.x, 0.f), &out[(size_t)(b0 + 2) * NB + n]);
        __builtin_nontemporal_store(fmaxf((float)s23.y, 0.f), &out[(size_t)(b0 + 3) * NB + n]);
    }
}

extern "C" void kernel_launch(void* const* d_in, const int* in_sizes, int n_in,
                              void* d_out, int out_size, void* d_ws, size_t ws_size,
                              hipStream_t stream) {
    const float* x   = (const float*)d_in[0];    // (B, N)
    const float* w   = (const float*)d_in[1];    // (N, DEG)
    const int*   idx = (const int*)d_in[2];      // (N, DEG)
    float* out = (float*)d_out;                  // (B, N)
    uint2* pw  = (uint2*)d_ws;                   // [16][N] = 2 MiB

    // allow 128 KiB dynamic LDS (idempotent; host-side, capture-safe)
    (void)hipFuncSetAttribute((const void*)gather4_kernel,
                              hipFuncAttributeMaxDynamicSharedMemorySize, 131072);

    prep_pw_kernel<<<NB / 64, 256, 0, stream>>>(idx, w, pw);

    gather4_kernel<<<256, 1024, 131072, stream>>>(x, pw, out);
}

// Round 2
// 83.629 us; speedup vs baseline: 1.0134x; 1.0134x over previous
//
#include <hip/hip_runtime.h>

// out[b,n] = relu( sum_d x[b, idx[n,d]] * w[n,d] )
//   x: (B=256, N=16384) f32, w: (N,32) f32, idx: (N,32) i32, out: (B,N) f32
//
// R11: R10 structure (direct x->LDS h2 quad image, ds_read_b64 gathers,
// pk_fma, split-major grid for XCD L2 reuse, NT out stores) with the pw
// stream layout widened: two d2-groups packed per uint4 element, so the
// hot loop issues 8 dwordx4 stream loads per n instead of 16 dwordx2.
// Prefetch is a full-iteration ping-pong (U/V 8xuint4 buffers): i+1's 8
// loads issue before compute(i), i=0's loads issue before __syncthreads
// (hidden under the staging drain). FP accumulation order is identical to
// R9/R10 (d2 ascending, lo-then-hi per d2, a=d2<8 / c=d2>=8 split).

#define NB   16384
#define DEG  32

typedef __fp16 hp2 __attribute__((ext_vector_type(2)));  // cvt_pkrtz result type

__device__ __forceinline__ unsigned pk16(float a, float b) {
    return __builtin_bit_cast(unsigned, (hp2)__builtin_amdgcn_cvt_pkrtz(a, b));
}

// prep: pack (idx,w) rows into 8 coalesced uint4 streams:
//   pw4[d4][n] = { idxpair(2*d4), wpair(2*d4), idxpair(2*d4+1), wpair(2*d4+1) }
// where idxpair(d2) = idx[n][2*d2] | idx[n][2*d2+1]<<16, wpair = pk16 of the
// matching w pair.  2 MiB total, same workspace budget as R10.
__global__ __launch_bounds__(256) void prep_pw_kernel(
    const int* __restrict__ idx, const float* __restrict__ w,
    uint4* __restrict__ pw4) {
    __shared__ int   idx_s[64][33];
    __shared__ float w_s[64][33];
    const int t  = threadIdx.x;
    const int nb = (int)blockIdx.x * 64;

    const int4*   src  = (const int4*)(idx + (size_t)nb * DEG);
    const float4* srcw = (const float4*)(w   + (size_t)nb * DEG);
#pragma unroll
    for (int p = 0; p < 2; ++p) {
        const int e4 = t + 256 * p;              // int4 index 0..511, coalesced
        const int n0 = e4 >> 3;
        const int c0 = (e4 & 7) * 4;
        const int4 v = src[e4];
        idx_s[n0][c0 + 0] = v.x; idx_s[n0][c0 + 1] = v.y;
        idx_s[n0][c0 + 2] = v.z; idx_s[n0][c0 + 3] = v.w;
        const float4 f = srcw[e4];
        w_s[n0][c0 + 0] = f.x; w_s[n0][c0 + 1] = f.y;
        w_s[n0][c0 + 2] = f.z; w_s[n0][c0 + 3] = f.w;
    }
    __syncthreads();

    const int np    = t & 63;
    const int dbase = t >> 6;                    // 0..3
#pragma unroll
    for (int k = 0; k < 2; ++k) {
        const int d4 = dbase * 2 + k;            // 0..7
        const int c  = 4 * d4;                   // first of 4 d-columns
        uint4 o;
        o.x = (unsigned)idx_s[np][c + 0] | ((unsigned)idx_s[np][c + 1] << 16);
        o.y = pk16(w_s[np][c + 0], w_s[np][c + 1]);
        o.z = (unsigned)idx_s[np][c + 2] | ((unsigned)idx_s[np][c + 3] << 16);
        o.w = pk16(w_s[np][c + 2], w_s[np][c + 3]);
        pw4[(size_t)d4 * NB + nb + np] = o;
    }
}

// Load all 8 uint4 streams for column nn into a register buffer.
#define LOADQ(buf, nn)                                                     \
    do {                                                                   \
        const uint4* p_ = pw4 + (nn);                                      \
        _Pragma("unroll") for (int d4_ = 0; d4_ < 8; ++d4_)                \
            buf[d4_] = p_[(size_t)d4_ * NB];                               \
    } while (0)

// Consume one uint4 = two d2-groups: 4 ds_read_b64 + 8 v_pk_fma_f16.
// FP order matches R9/R10 exactly (d2 even then odd; lo-j then hi-j).
#define ACC2(buf, D4, r01, r23)                                            \
    {                                                                      \
        const unsigned jpA = buf[D4].x;                                    \
        const uint2 gA0 = lds[jpA & 0xffffu];                              \
        const uint2 gA1 = lds[jpA >> 16];                                  \
        const hp2 wA  = __builtin_bit_cast(hp2, buf[D4].y);                \
        const hp2 wAlo = {wA.x, wA.x};                                     \
        const hp2 wAhi = {wA.y, wA.y};                                     \
        r01 += wAlo * __builtin_bit_cast(hp2, gA0.x);                      \
        r23 += wAlo * __builtin_bit_cast(hp2, gA0.y);                      \
        r01 += wAhi * __builtin_bit_cast(hp2, gA1.x);                      \
        r23 += wAhi * __builtin_bit_cast(hp2, gA1.y);                      \
        const unsigned jpB = buf[D4].z;                                    \
        const uint2 gB0 = lds[jpB & 0xffffu];                              \
        const uint2 gB1 = lds[jpB >> 16];                                  \
        const hp2 wB  = __builtin_bit_cast(hp2, buf[D4].w);                \
        const hp2 wBlo = {wB.x, wB.x};                                     \
        const hp2 wBhi = {wB.y, wB.y};                                     \
        r01 += wBlo * __builtin_bit_cast(hp2, gB0.x);                      \
        r23 += wBlo * __builtin_bit_cast(hp2, gB0.y);                      \
        r01 += wBhi * __builtin_bit_cast(hp2, gB1.x);                      \
        r23 += wBhi * __builtin_bit_cast(hp2, gB1.y);                      \
    }

// One i-iteration: optional prefetch of the NEXT iteration's 8 streams into
// NXT, then compute from CUR (vmcnt waits cover CUR only; NXT stays in
// flight across the whole compute phase).
#define STEP(CUR, NXT, I, PF)                                              \
    {                                                                      \
        const int n = n0 + t + 1024 * (I);                                 \
        if (PF) LOADQ(NXT, n + 1024);                                      \
        hp2 a01 = {0, 0}, a23 = {0, 0}, c01 = {0, 0}, c23 = {0, 0};        \
        ACC2(CUR, 0, a01, a23)                                             \
        ACC2(CUR, 1, a01, a23)                                             \
        ACC2(CUR, 2, a01, a23)                                             \
        ACC2(CUR, 3, a01, a23)                                             \
        ACC2(CUR, 4, c01, c23)                                             \
        ACC2(CUR, 5, c01, c23)                                             \
        ACC2(CUR, 6, c01, c23)                                             \
        ACC2(CUR, 7, c01, c23)                                             \
        const hp2 s01 = a01 + c01;                                         \
        const hp2 s23 = a23 + c23;                                         \
        __builtin_nontemporal_store(fmaxf((float)s01.x, 0.f),              \
                                    &out[(size_t)(b0 + 0) * NB + n]);      \
        __builtin_nontemporal_store(fmaxf((float)s01.y, 0.f),              \
                                    &out[(size_t)(b0 + 1) * NB + n]);      \
        __builtin_nontemporal_store(fmaxf((float)s23.x, 0.f),              \
                                    &out[(size_t)(b0 + 2) * NB + n]);      \
        __builtin_nontemporal_store(fmaxf((float)s23.y, 0.f),              \
                                    &out[(size_t)(b0 + 3) * NB + n]);      \
    }

__global__ __launch_bounds__(1024, 4) void gather4_kernel(
    const float* __restrict__ x, const uint4* __restrict__ pw4,
    float* __restrict__ out) {
    extern __shared__ uint2 lds[];               // 16384 uint2 = 128 KiB
    const int t  = threadIdx.x;
    const int q  = (int)blockIdx.x & 63;         // quad 0..63 -> b = 4q..4q+3
    const int n0 = ((int)blockIdx.x >> 6) * 4096;  // split-major: XCD = q%8

    // Stage quad j-image straight from x (coalesced float4 per row; rows are
    // L2-hot for 3 of the 4 split-blocks). ds_write_b128 stride-32B: clean.
    const float* xr0 = x + (size_t)(4 * q) * NB;
    const float* xr1 = xr0 + NB;
    const float* xr2 = xr1 + NB;
    const float* xr3 = xr2 + NB;
#pragma unroll
    for (int p = 0; p < 4; ++p) {
        const int j = 4 * (t + 1024 * p);
        const float4 r0 = *(const float4*)&xr0[j];
        const float4 r1 = *(const float4*)&xr1[j];
        const float4 r2 = *(const float4*)&xr2[j];
        const float4 r3 = *(const float4*)&xr3[j];
        uint4 w0, w1;
        w0.x = pk16(r0.x, r1.x); w0.y = pk16(r2.x, r3.x);
        w0.z = pk16(r0.y, r1.y); w0.w = pk16(r2.y, r3.y);
        w1.x = pk16(r0.z, r1.z); w1.y = pk16(r2.z, r3.z);
        w1.z = pk16(r0.w, r1.w); w1.w = pk16(r2.w, r3.w);
        *(uint4*)&lds[j]     = w0;
        *(uint4*)&lds[j + 2] = w1;
    }

    uint4 U[8], V[8];
    // Prefetch i=0's streams before the barrier: L2 latency hides under the
    // staging lgkmcnt drain + barrier.
    LOADQ(U, n0 + t);
    __syncthreads();

    const int b0 = 4 * q;
    STEP(U, V, 0, 1)
    STEP(V, U, 1, 1)
    STEP(U, V, 2, 1)
    STEP(V, U, 3, 0)
}

extern "C" void kernel_launch(void* const* d_in, const int* in_sizes, int n_in,
                              void* d_out, int out_size, void* d_ws, size_t ws_size,
                              hipStream_t stream) {
    const float* x   = (const float*)d_in[0];    // (B, N)
    const float* w   = (const float*)d_in[1];    // (N, DEG)
    const int*   idx = (const int*)d_in[2];      // (N, DEG)
    float* out = (float*)d_out;                  // (B, N)
    uint4* pw4 = (uint4*)d_ws;                   // [8][N] uint4 = 2 MiB

    // allow 128 KiB dynamic LDS (idempotent; host-side, capture-safe)
    (void)hipFuncSetAttribute((const void*)gather4_kernel,
                              hipFuncAttributeMaxDynamicSharedMemorySize, 131072);

    prep_pw_kernel<<<NB / 64, 256, 0, stream>>>(idx, w, pw4);

    gather4_kernel<<<256, 1024, 131072, stream>>>(x, pw4, out);
}